// Round 1
// baseline (567.347 us; speedup 1.0000x reference)
//
#include <hip/hip_runtime.h>

// Problem constants (match reference)
#define BG   8          // graphs
#define NN   10000      // nodes per graph
#define EE   320000     // edges per graph
#define CC   128        // channels (in == out)
#define BN   (BG*NN)    // 80000
#define BE   (BG*EE)    // 2560000

// ---------------------------------------------------------------------------
// Workspace layout (all 4-byte elements):
//   [0,      BN)  deg      (f32)  row-sum of edge_val per (b, row)
//   [BN,    2BN)  counts   (int)  edges per (b, row)        <- memset 0 each call
//   [2BN,   3BN)  offsets  (int)  exclusive scan of counts (per graph)
//   [3BN,   4BN)  cursor   (int)  scratch copy of offsets for fill
//   [4BN, 4BN+BE) csr_col  (int)  edge cols sorted by row
//   [4BN+BE, 4BN+2BE) csr_val (f32)
// total = 4*80000 + 2*2560000 = 5,440,000 elems = 21.76 MB
// aggx (Σ v·x[col]) is accumulated straight into d_out (overwritten by k_gemm).
// ---------------------------------------------------------------------------

__global__ __launch_bounds__(256) void k_hist(const int* __restrict__ edge_row,
                                              int* __restrict__ counts) {
    int bid = blockIdx.x;
    int b = bid / (EE / 256);                 // 1250 blocks per graph
    int e = (bid % (EE / 256)) * 256 + threadIdx.x;
    int r = edge_row[(size_t)b * EE + e];
    atomicAdd(&counts[b * NN + r], 1);
}

__global__ __launch_bounds__(1024) void k_scan(const int* __restrict__ counts,
                                               int* __restrict__ offsets,
                                               int* __restrict__ cursor) {
    int b = blockIdx.x;
    const int* c = counts + b * NN;
    int* o = offsets + b * NN;
    int* cur = cursor + b * NN;
    int t = threadIdx.x;
    int base = t * 10;                        // 1000 threads cover N=10000
    int local[10];
    int sum = 0;
    if (base < NN) {
#pragma unroll
        for (int j = 0; j < 10; j++) {
            int idx = base + j;
            int v = (idx < NN) ? c[idx] : 0;
            local[j] = sum;                   // exclusive within thread
            sum += v;
        }
    }
    // block exclusive scan of per-thread sums (1024 threads = 16 waves)
    int lane = t & 63, wid = t >> 6;
    int v = sum;
#pragma unroll
    for (int d = 1; d < 64; d <<= 1) {
        int n = __shfl_up(v, d);
        if (lane >= d) v += n;
    }
    __shared__ int wsum[16];
    if (lane == 63) wsum[wid] = v;
    __syncthreads();
    if (t == 0) {
        int acc = 0;
#pragma unroll
        for (int i = 0; i < 16; i++) { int x = wsum[i]; wsum[i] = acc; acc += x; }
    }
    __syncthreads();
    int excl = wsum[wid] + (v - sum);         // exclusive prefix of this thread
    if (base < NN) {
#pragma unroll
        for (int j = 0; j < 10; j++) {
            int idx = base + j;
            if (idx < NN) { int val = excl + local[j]; o[idx] = val; cur[idx] = val; }
        }
    }
}

__global__ __launch_bounds__(256) void k_fill(const int* __restrict__ edge_row,
                                              const int* __restrict__ edge_col,
                                              const float* __restrict__ edge_val,
                                              int* __restrict__ cursor,
                                              int* __restrict__ csr_col,
                                              float* __restrict__ csr_val) {
    int bid = blockIdx.x;
    int b = bid / (EE / 256);
    int e = (bid % (EE / 256)) * 256 + threadIdx.x;
    size_t gi = (size_t)b * EE + e;
    int r = edge_row[gi];
    int pos = atomicAdd(&cursor[b * NN + r], 1);
    size_t ci = (size_t)b * EE + pos;
    csr_col[ci] = edge_col[gi];
    csr_val[ci] = edge_val[gi];
}

// One wave per output row; lane owns channels {2*lane, 2*lane+1}.
// aggx (=d_out) gets Sum_e val*x[col][ch]; deg gets Sum_e val.
__global__ __launch_bounds__(256) void k_gather(const float* __restrict__ x,
                                                const int* __restrict__ offsets,
                                                const int* __restrict__ counts,
                                                const int* __restrict__ csr_col,
                                                const float* __restrict__ csr_val,
                                                float* __restrict__ aggx,
                                                float* __restrict__ deg) {
    int bid = blockIdx.x;
    int b = bid & 7;                          // graph -> XCD locality
    int chunk = bid >> 3;                     // 0..2499
    int wid = threadIdx.x >> 6;
    int lane = threadIdx.x & 63;
    int r = chunk * 4 + wid;
    int bn = b * NN + r;
    int start = offsets[bn];
    int len = counts[bn];
    const float* xb = x + (size_t)b * NN * CC;
    const int* colp = csr_col + (size_t)b * EE + start;
    const float* valp = csr_val + (size_t)b * EE + start;

    float2 acc0 = make_float2(0.f, 0.f), acc1 = make_float2(0.f, 0.f);
    float dsum = 0.f;
    for (int base = 0; base < len; base += 64) {
        int c_l = 0; float v_l = 0.f;
        if (base + lane < len) { c_l = colp[base + lane]; v_l = valp[base + lane]; }
        int m = len - base; if (m > 64) m = 64;
        int mm = (m + 3) & ~3;
        for (int e = 0; e < mm; e += 4) {
            int c0 = __shfl(c_l, e + 0); float v0 = __shfl(v_l, e + 0);
            int c1 = __shfl(c_l, e + 1); float v1 = __shfl(v_l, e + 1);
            int c2 = __shfl(c_l, e + 2); float v2 = __shfl(v_l, e + 2);
            int c3 = __shfl(c_l, e + 3); float v3 = __shfl(v_l, e + 3);
            float2 x0 = *(const float2*)(xb + (size_t)c0 * CC + 2 * lane);
            float2 x1 = *(const float2*)(xb + (size_t)c1 * CC + 2 * lane);
            float2 x2 = *(const float2*)(xb + (size_t)c2 * CC + 2 * lane);
            float2 x3 = *(const float2*)(xb + (size_t)c3 * CC + 2 * lane);
            acc0.x += v0 * x0.x; acc0.y += v0 * x0.y;
            acc1.x += v1 * x1.x; acc1.y += v1 * x1.y;
            acc0.x += v2 * x2.x; acc0.y += v2 * x2.y;
            acc1.x += v3 * x3.x; acc1.y += v3 * x3.y;
            dsum += v0 + v1 + v2 + v3;
        }
    }
    float2 res = make_float2(acc0.x + acc1.x, acc0.y + acc1.y);
    float* outp = aggx + (size_t)bn * CC;
    *(float2*)(outp + 2 * lane) = res;
    if (lane == 0) deg[bn] = dsum;
}

// out[row] = mask * (aggx[row] @ W + deg*bias) / max(deg,1)
// 64 rows x 128 cols per block; thread tile 4 rows x 8 cols.
// aggx tile staged in LDS (in-place with output: stage fully, sync, compute).
__global__ __launch_bounds__(256) void k_gemm(float* __restrict__ io,
                                              const float* __restrict__ W,
                                              const float* __restrict__ bias,
                                              const float* __restrict__ deg,
                                              const int* __restrict__ num_nodes) {
    __shared__ float at[64][132];             // +4 pad: row-group reads hit 2 banks
    int t = threadIdx.x;
    int row0 = blockIdx.x * 64;

    const float4* src = (const float4*)(io + (size_t)row0 * CC);
#pragma unroll
    for (int i = 0; i < 8; i++) {
        int f4 = t + i * 256;                 // 0..2047 float4s in the tile
        float4 v = src[f4];
        int row = f4 >> 5;                    // 32 float4 per row
        int col4 = f4 & 31;
        *(float4*)(&at[row][col4 * 4]) = v;
    }
    __syncthreads();

    int cg = t & 15;                          // cols 8*cg .. 8*cg+7
    int rg = t >> 4;                          // rows 4*rg .. 4*rg+3
    float acc[4][8] = {};
#pragma unroll 4
    for (int k = 0; k < 128; k++) {
        float4 w0 = *(const float4*)(W + k * 128 + cg * 8);
        float4 w1 = *(const float4*)(W + k * 128 + cg * 8 + 4);
        float a0 = at[rg * 4 + 0][k];
        float a1 = at[rg * 4 + 1][k];
        float a2 = at[rg * 4 + 2][k];
        float a3 = at[rg * 4 + 3][k];
        acc[0][0] += a0 * w0.x; acc[0][1] += a0 * w0.y; acc[0][2] += a0 * w0.z; acc[0][3] += a0 * w0.w;
        acc[0][4] += a0 * w1.x; acc[0][5] += a0 * w1.y; acc[0][6] += a0 * w1.z; acc[0][7] += a0 * w1.w;
        acc[1][0] += a1 * w0.x; acc[1][1] += a1 * w0.y; acc[1][2] += a1 * w0.z; acc[1][3] += a1 * w0.w;
        acc[1][4] += a1 * w1.x; acc[1][5] += a1 * w1.y; acc[1][6] += a1 * w1.z; acc[1][7] += a1 * w1.w;
        acc[2][0] += a2 * w0.x; acc[2][1] += a2 * w0.y; acc[2][2] += a2 * w0.z; acc[2][3] += a2 * w0.w;
        acc[2][4] += a2 * w1.x; acc[2][5] += a2 * w1.y; acc[2][6] += a2 * w1.z; acc[2][7] += a2 * w1.w;
        acc[3][0] += a3 * w0.x; acc[3][1] += a3 * w0.y; acc[3][2] += a3 * w0.z; acc[3][3] += a3 * w0.w;
        acc[3][4] += a3 * w1.x; acc[3][5] += a3 * w1.y; acc[3][6] += a3 * w1.z; acc[3][7] += a3 * w1.w;
    }

    float4 b0 = *(const float4*)(bias + cg * 8);
    float4 b1 = *(const float4*)(bias + cg * 8 + 4);
    float bb[8] = { b0.x, b0.y, b0.z, b0.w, b1.x, b1.y, b1.z, b1.w };

#pragma unroll
    for (int i = 0; i < 4; i++) {
        int grow = row0 + rg * 4 + i;
        int b = grow / NN;
        int r = grow - b * NN;
        float d = deg[grow];
        float sc = 1.0f / fmaxf(d, 1.0f);
        bool alive = r < num_nodes[b];
        float o[8];
#pragma unroll
        for (int j = 0; j < 8; j++)
            o[j] = alive ? (acc[i][j] + d * bb[j]) * sc : 0.0f;
        float* dst = io + (size_t)grow * CC + cg * 8;
        *(float4*)(dst)     = make_float4(o[0], o[1], o[2], o[3]);
        *(float4*)(dst + 4) = make_float4(o[4], o[5], o[6], o[7]);
    }
}

extern "C" void kernel_launch(void* const* d_in, const int* in_sizes, int n_in,
                              void* d_out, int out_size, void* d_ws, size_t ws_size,
                              hipStream_t stream) {
    const float* x        = (const float*)d_in[0];
    const float* weight   = (const float*)d_in[1];
    const float* bias     = (const float*)d_in[2];
    const int*   edge_row = (const int*)d_in[3];
    const int*   edge_col = (const int*)d_in[4];
    const float* edge_val = (const float*)d_in[5];
    const int*   num_nodes= (const int*)d_in[6];
    float* out = (float*)d_out;

    float* deg     = (float*)d_ws;
    int*   counts  = (int*)d_ws + BN;
    int*   offsets = (int*)d_ws + 2 * BN;
    int*   cursor  = (int*)d_ws + 3 * BN;
    int*   csr_col = (int*)d_ws + 4 * BN;
    float* csr_val = (float*)d_ws + 4 * BN + BE;

    hipMemsetAsync(counts, 0, BN * sizeof(int), stream);
    k_hist<<<BG * (EE / 256), 256, 0, stream>>>(edge_row, counts);
    k_scan<<<BG, 1024, 0, stream>>>(counts, offsets, cursor);
    k_fill<<<BG * (EE / 256), 256, 0, stream>>>(edge_row, edge_col, edge_val,
                                                cursor, csr_col, csr_val);
    k_gather<<<8 * (NN / 4), 256, 0, stream>>>(x, offsets, counts, csr_col,
                                               csr_val, out, deg);
    k_gemm<<<BN / 64, 256, 0, stream>>>(out, weight, bias, deg, num_nodes);
}